// Round 16
// baseline (1473.128 us; speedup 1.0000x reference)
//
#include <hip/hip_runtime.h>

typedef __bf16 bf16_t;
typedef __attribute__((ext_vector_type(8))) __bf16 bf16x8;
typedef __attribute__((ext_vector_type(4))) float f32x4;
typedef __attribute__((ext_vector_type(4))) unsigned int u32x4;

#define NSEQ 1024
#define SLEN 100
#define HID  512

union HU { u32x4 u; bf16x8 h; };

__device__ __forceinline__ float sigf(float x) { return 1.0f / (1.0f + __expf(-x)); }
__device__ __forceinline__ float tanh_(float x) { return 1.0f - 2.0f / (__expf(2.0f * x) + 1.0f); }

__device__ __forceinline__ bf16x8 cvt8(float4 a, float4 b) {
    bf16x8 v;
    v[0] = (__bf16)a.x; v[1] = (__bf16)a.y; v[2] = (__bf16)a.z; v[3] = (__bf16)a.w;
    v[4] = (__bf16)b.x; v[5] = (__bf16)b.y; v[6] = (__bf16)b.z; v[7] = (__bf16)b.w;
    return v;
}

// ---------------------------------------------------------------------------
// Embedding GEMM: emb[t][seq][h] = sum_d x[seq][t][d] * W_e[h][d] + b_e[h]
// ---------------------------------------------------------------------------
__global__ __launch_bounds__(256)
void embed_kernel(const float* __restrict__ x, const float* __restrict__ We,
                  const float* __restrict__ be, bf16_t* __restrict__ emb)
{
    __shared__ bf16_t bsm[8 * 256 * 8];   // [q=k/8][col][8] bf16 = 32 KB
    const int bid = blockIdx.x;
    const int rowblk = bid >> 1;
    const int col0 = (bid & 1) << 8;
    const int tid = threadIdx.x;

    {
        const int col = tid;  // 0..255
        const float* src = We + (size_t)(col0 + col) * 64;
        #pragma unroll
        for (int q = 0; q < 8; ++q) {
            float4 f0 = *(const float4*)(src + q * 8);
            float4 f1 = *(const float4*)(src + q * 8 + 4);
            *(bf16x8*)&bsm[(q * 256 + col) * 8] = cvt8(f0, f1);
        }
    }
    __syncthreads();

    const int l = tid & 63, w = tid >> 6;
    const int lo = l & 15, hi = l >> 4;
    const int rowbase = rowblk * 64 + w * 16;
    const int row_a = rowbase + lo;
    const int seq = row_a & (NSEQ - 1);
    const int t = row_a >> 10;
    const float* xrow = x + ((size_t)seq * SLEN + t) * 64;

    bf16x8 a0, a1;
    {
        const float* p = xrow + hi * 8;
        a0 = cvt8(*(const float4*)p, *(const float4*)(p + 4));
        p = xrow + 32 + hi * 8;
        a1 = cvt8(*(const float4*)p, *(const float4*)(p + 4));
    }

    #pragma unroll
    for (int nf = 0; nf < 16; ++nf) {
        f32x4 acc = {0.f, 0.f, 0.f, 0.f};
        bf16x8 b0 = *(const bf16x8*)&bsm[((0 * 4 + hi) * 256 + nf * 16 + lo) * 8];
        bf16x8 b1 = *(const bf16x8*)&bsm[((1 * 4 + hi) * 256 + nf * 16 + lo) * 8];
        acc = __builtin_amdgcn_mfma_f32_16x16x32_bf16(a0, b0, acc, 0, 0, 0);
        acc = __builtin_amdgcn_mfma_f32_16x16x32_bf16(a1, b1, acc, 0, 0, 0);
        const int col = col0 + nf * 16 + lo;
        const float bias = be[col];
        #pragma unroll
        for (int r = 0; r < 4; ++r) {
            const int rr = rowbase + hi * 4 + r;
            emb[(size_t)rr * HID + col] = (bf16_t)(acc[r] + bias);
        }
    }
}

// ---------------------------------------------------------------------------
// Persistent masked-LSTM. 256 blocks x 512 threads, 128 KB LDS, 1 block/CU.
// Group m = bid&7 (32 blocks, XCD-local with round-robin dispatch; verified
// at runtime via HW_REG_XCC_ID). Fast path: h exchanged via L1-bypass (sc0)
// loads through the shared per-XCD L2 — no per-step L2 invalidate/writeback.
// Agent-scope fallback if the group spans XCDs.
// Wave = 16 seqs x 64 gate-cols (4 N-frags = i,f,g,o at 16 units); cell
// update fully lane-local; weights LDS-resident. h-loads pipelined with
// counted vmcnt(12/8/4/0) (T4); sched_barrier(0) after each wait (rule #18).
// e-loads exec-masked per lane.
// R16 = R13 + kt{2,3} B-cache parked in AGPRs: the allocator hard-caps arch
// VGPRs at 128 (R14/R15 spilled 136 MB trying to exceed it), but AGPRs are
// budgeted separately and gfx950 MFMA reads B from AGPR directly. Combined
// file ~128 arch + 64 acc = 192 <= 256 -> still 8 waves/CU, no spill.
// LDS reads 896 -> 768 per CU per step.
// ---------------------------------------------------------------------------
__global__ __launch_bounds__(512)
void lstm_kernel(const bf16_t* __restrict__ emb, const int* __restrict__ mask,
                 const float* __restrict__ Wih, const float* __restrict__ Whh,
                 const float* __restrict__ bih, const float* __restrict__ bhh,
                 const float* __restrict__ h0, const float* __restrict__ c0,
                 bf16_t* __restrict__ hbuf,        // [2][1024][512] bf16
                 unsigned int* __restrict__ cnt,   // [0..511] counters, [512..519] xcd masks
                 float* __restrict__ out)
{
    extern __shared__ bf16_t wsm[];   // [q=k/8 (128)][col (64)][8] = 128 KB
    const int bid = blockIdx.x;
    const int m = bid & 7;            // group (XCD-local with round-robin dispatch)
    const int jsl = bid >> 3;         // 0..31
    const int jbase = jsl * 16;       // 16 hidden units per block
    const int tid = threadIdx.x;

    // publish this block's XCD id into the group's mask (before init arrival)
    unsigned xcc = 0;
    asm volatile("s_getreg_b32 %0, hwreg(HW_REG_XCC_ID)" : "=s"(xcc));
    if (tid == 0)
        __hip_atomic_fetch_or(&cnt[512 + m], 1u << (xcc & 31u),
                              __ATOMIC_RELAXED, __HIP_MEMORY_SCOPE_AGENT);

    // ---- stage weight slice: wsm[q][col][e] = Wcat[G(col)][q*8+e] ----
    {
        const int col = tid & 63;
        const int qg = tid >> 6;          // 0..7
        const int grp = col >> 4;
        const int jj = col & 15;
        const int G = grp * 512 + jbase + jj;
        #pragma unroll
        for (int i = 0; i < 16; ++i) {
            const int q = qg * 16 + i;    // 0..127
            const int k0 = q * 8;
            const float* src = (k0 < 512) ? (Wih + (size_t)G * 512 + k0)
                                          : (Whh + (size_t)G * 512 + (k0 - 512));
            float4 f0 = *(const float4*)src;
            float4 f1 = *(const float4*)(src + 4);
            *(bf16x8*)&wsm[(q * 64 + col) * 8] = cvt8(f0, f1);
        }
    }

    const int lane = tid & 63, w = tid >> 6;
    const int lo = lane & 15, hi = lane >> 4;
    const int seqbase = m * 128 + w * 16;
    const int jg = jbase + lo;
    const int seq_a = seqbase + lo;       // this lane's A row
    const int koff = hi * 8;

    float bs[4];
    #pragma unroll
    for (int g = 0; g < 4; ++g) bs[g] = bih[g * 512 + jg] + bhh[g * 512 + jg];

    // init c and h(0) = mask0 ? emb0 : h0
    float c_reg[4];
    const float c0v = c0[jg], h0v = h0[jg];
    #pragma unroll
    for (int r = 0; r < 4; ++r) {
        const int seq = seqbase + hi * 4 + r;
        c_reg[r] = c0v;
        const int mb0 = mask[(size_t)seq * SLEN + 0];
        const float e0 = (float)emb[(size_t)seq * HID + jg];
        hbuf[(size_t)seq * HID + jg] = (bf16_t)(mb0 ? e0 : h0v);
    }
    __syncthreads();
    if (tid == 0)
        __hip_atomic_fetch_add(&cnt[m * 64], 1u, __ATOMIC_RELEASE,
                               __HIP_MEMORY_SCOPE_AGENT);

    #define BFRAG_L(kt, nf) (*(const bf16x8*)&wsm[(((kt) * 4 + hi) * 64 + (nf) * 16 + lo) * 8])
    #define BFRAG_H(kt, nf) (*(const bf16x8*)&wsm[((((kt) + 16) * 4 + hi) * 64 + (nf) * 16 + lo) * 8])

    // ---- persistent B-frag cache: kt 0,1 in VGPRs (R13-proven) ----
    HU bcL[2][4], bcH[2][4];
    #pragma unroll
    for (int kt = 0; kt < 2; ++kt) {
        #pragma unroll
        for (int nf = 0; nf < 4; ++nf) {
            bcL[kt][nf].h = BFRAG_L(kt, nf);
            bcH[kt][nf].h = BFRAG_H(kt, nf);
            asm volatile("" : "+v"(bcL[kt][nf].u));   // pin: no remat from LDS
            asm volatile("" : "+v"(bcH[kt][nf].u));
        }
    }
    // ---- kt 2,3 parked in AGPRs (separate allocation; MFMA reads B from a) ----
    HU bcL2[2][4], bcH2[2][4];
    #pragma unroll
    for (int k2 = 0; k2 < 2; ++k2) {
        #pragma unroll
        for (int nf = 0; nf < 4; ++nf) {
            bcL2[k2][nf].h = BFRAG_L(k2 + 2, nf);
            bcH2[k2][nf].h = BFRAG_H(k2 + 2, nf);
            asm volatile("" : "+a"(bcL2[k2][nf].u));  // pin into AGPR file
            asm volatile("" : "+a"(bcH2[k2][nf].u));
        }
    }

    bool fast = false;

    for (int t = 0; t < SLEN; ++t) {
        // ---- prefetch (h-independent) before the barrier: mask + emb frags.
        //      e-loads exec-masked: mb=0 lanes never use ex, so skip the fetch.
        const int mb = mask[(size_t)seq_a * SLEN + t];
        const bf16_t* erow = emb + ((size_t)t * NSEQ + seq_a) * HID + koff;
        bf16x8 ex[16];
        if (mb) {
            #pragma unroll
            for (int kt = 0; kt < 16; ++kt)
                ex[kt] = *(const bf16x8*)(erow + kt * 32);
        }

        // ---- group barrier ----
        if (tid == 0) {
            const unsigned target = 32u * (unsigned)(t + 1);
            unsigned it = 0;
            while (__hip_atomic_load(&cnt[m * 64], __ATOMIC_RELAXED,
                                     __HIP_MEMORY_SCOPE_AGENT) < target &&
                   ++it < (1u << 27)) {
                __builtin_amdgcn_s_sleep(1);
            }
            if (!fast)   // slow path: agent acquire (L2 invalidate)
                (void)__hip_atomic_load(&cnt[m * 64], __ATOMIC_ACQUIRE,
                                        __HIP_MEMORY_SCOPE_AGENT);
        }
        __syncthreads();
        if (t == 0) {
            const unsigned gm = __hip_atomic_load(&cnt[512 + m], __ATOMIC_RELAXED,
                                                  __HIP_MEMORY_SCOPE_AGENT);
            fast = (__popc(gm) == 1);   // uniform across block
        }

        const bf16_t* hb_r = hbuf + (size_t)(t & 1) * (NSEQ * HID);
        bf16_t* hb_w = hbuf + (size_t)((t + 1) & 1) * (NSEQ * HID);
        const unsigned long long hrow =
            (unsigned long long)(hb_r + (size_t)seq_a * HID + koff);

        // ---- h loads: issue all 16 (sc0, L1-bypass), consume in 4-kt
        //      segments gated by counted vmcnt (pipelined, T4) ----
        HU h_[16];
        #define HL(i, OFF) \
            asm volatile("global_load_dwordx4 %0, %1, off offset:" OFF " sc0" \
                         : "=v"(h_[i].u) : "v"(hrow));
        HL(0, "0")    HL(1, "64")   HL(2, "128")  HL(3, "192")
        HL(4, "256")  HL(5, "320")  HL(6, "384")  HL(7, "448")
        HL(8, "512")  HL(9, "576")  HL(10, "640") HL(11, "704")
        HL(12, "768") HL(13, "832") HL(14, "896") HL(15, "960")
        #undef HL

        f32x4 acc[4];
        #pragma unroll
        for (int nf = 0; nf < 4; ++nf) acc[nf] = (f32x4){0.f, 0.f, 0.f, 0.f};

        // per-kt body: x-half (select) + h-half, both consuming h_[kt].
        #define KT_ONE(kt, BL0, BL1, BL2, BL3, BH0, BH1, BH2, BH3)                       \
            {                                                                            \
                const bf16x8 a = mb ? ex[kt] : h_[kt].h;                                 \
                acc[0] = __builtin_amdgcn_mfma_f32_16x16x32_bf16(a, BL0, acc[0], 0, 0, 0); \
                acc[1] = __builtin_amdgcn_mfma_f32_16x16x32_bf16(a, BL1, acc[1], 0, 0, 0); \
                acc[2] = __builtin_amdgcn_mfma_f32_16x16x32_bf16(a, BL2, acc[2], 0, 0, 0); \
                acc[3] = __builtin_amdgcn_mfma_f32_16x16x32_bf16(a, BL3, acc[3], 0, 0, 0); \
                acc[0] = __builtin_amdgcn_mfma_f32_16x16x32_bf16(h_[kt].h, BH0, acc[0], 0, 0, 0); \
                acc[1] = __builtin_amdgcn_mfma_f32_16x16x32_bf16(h_[kt].h, BH1, acc[1], 0, 0, 0); \
                acc[2] = __builtin_amdgcn_mfma_f32_16x16x32_bf16(h_[kt].h, BH2, acc[2], 0, 0, 0); \
                acc[3] = __builtin_amdgcn_mfma_f32_16x16x32_bf16(h_[kt].h, BH3, acc[3], 0, 0, 0); \
            }
        #define KT_LDS(kt) KT_ONE(kt, BFRAG_L(kt, 0), BFRAG_L(kt, 1), BFRAG_L(kt, 2), BFRAG_L(kt, 3), \
                                       BFRAG_H(kt, 0), BFRAG_H(kt, 1), BFRAG_H(kt, 2), BFRAG_H(kt, 3))
        #define WAITSB(VMC) \
            asm volatile("s_waitcnt vmcnt(" VMC ")" ::: "memory"); \
            __builtin_amdgcn_sched_barrier(0);

        WAITSB("12")
        KT_ONE(0, bcL[0][0].h, bcL[0][1].h, bcL[0][2].h, bcL[0][3].h,
                  bcH[0][0].h, bcH[0][1].h, bcH[0][2].h, bcH[0][3].h)
        KT_ONE(1, bcL[1][0].h, bcL[1][1].h, bcL[1][2].h, bcL[1][3].h,
                  bcH[1][0].h, bcH[1][1].h, bcH[1][2].h, bcH[1][3].h)
        KT_ONE(2, bcL2[0][0].h, bcL2[0][1].h, bcL2[0][2].h, bcL2[0][3].h,
                  bcH2[0][0].h, bcH2[0][1].h, bcH2[0][2].h, bcH2[0][3].h)
        KT_ONE(3, bcL2[1][0].h, bcL2[1][1].h, bcL2[1][2].h, bcL2[1][3].h,
                  bcH2[1][0].h, bcH2[1][1].h, bcH2[1][2].h, bcH2[1][3].h)
        WAITSB("8")
        KT_LDS(4) KT_LDS(5) KT_LDS(6) KT_LDS(7)
        WAITSB("4")
        KT_LDS(8) KT_LDS(9) KT_LDS(10) KT_LDS(11)
        WAITSB("0")
        KT_LDS(12) KT_LDS(13) KT_LDS(14) KT_LDS(15)
        #undef KT_ONE
        #undef KT_LDS
        #undef WAITSB

        // ---- lane-local LSTM cell update (acc[0..3] = i,f,g,o at unit jg) ----
        #pragma unroll
        for (int r = 0; r < 4; ++r) {
            const float iv = acc[0][r] + bs[0];
            const float fv = acc[1][r] + bs[1];
            const float gv = acc[2][r] + bs[2];
            const float ov = acc[3][r] + bs[3];
            const float cn = sigf(fv) * c_reg[r] + sigf(iv) * tanh_(gv);
            c_reg[r] = cn;
            const float hv = sigf(ov) * tanh_(cn);
            const int s = seqbase + hi * 4 + r;
            hb_w[(size_t)s * HID + jg] = (bf16_t)hv;
            if (t == SLEN - 1) out[(size_t)s * HID + jg] = hv;
        }
        __syncthreads();   // drains h stores (vmcnt 0) before the counter bump
        if (tid == 0) {
            if (fast)
                __hip_atomic_fetch_add(&cnt[m * 64], 1u, __ATOMIC_RELAXED,
                                       __HIP_MEMORY_SCOPE_AGENT);
            else
                __hip_atomic_fetch_add(&cnt[m * 64], 1u, __ATOMIC_RELEASE,
                                       __HIP_MEMORY_SCOPE_AGENT);
        }
    }
    #undef BFRAG_L
    #undef BFRAG_H
}

// ---------------------------------------------------------------------------
extern "C" void kernel_launch(void* const* d_in, const int* in_sizes, int n_in,
                              void* d_out, int out_size, void* d_ws, size_t ws_size,
                              hipStream_t stream)
{
    const float* x    = (const float*)d_in[0];
    const int*   mask = (const int*)d_in[1];
    const float* We   = (const float*)d_in[2];
    const float* be   = (const float*)d_in[3];
    const float* Wih  = (const float*)d_in[4];
    const float* Whh  = (const float*)d_in[5];
    const float* bih  = (const float*)d_in[6];
    const float* bhh  = (const float*)d_in[7];
    const float* h0   = (const float*)d_in[8];
    const float* c0   = (const float*)d_in[9];
    float* out = (float*)d_out;

    unsigned char* ws = (unsigned char*)d_ws;
    unsigned int* cnt = (unsigned int*)ws;                       // 4 KB
    bf16_t* hbuf = (bf16_t*)(ws + 4096);                         // 2 MB
    bf16_t* emb  = (bf16_t*)(ws + 4096 + (size_t)2 * NSEQ * HID * 2);  // ~100 MB

    hipMemsetAsync(cnt, 0, 4096, stream);

    embed_kernel<<<3200, 256, 0, stream>>>(x, We, be, emb);

    hipFuncSetAttribute(reinterpret_cast<const void*>(lstm_kernel),
                        hipFuncAttributeMaxDynamicSharedMemorySize, 131072);
    lstm_kernel<<<256, 512, 131072, stream>>>(emb, mask, Wih, Whh, bih, bhh,
                                              h0, c0, hbuf, cnt, out);
}

// Round 17
// 939.523 us; speedup vs baseline: 1.5680x; 1.5680x over previous
//
#include <hip/hip_runtime.h>

typedef __bf16 bf16_t;
typedef __attribute__((ext_vector_type(8))) __bf16 bf16x8;
typedef __attribute__((ext_vector_type(4))) float f32x4;
typedef __attribute__((ext_vector_type(4))) unsigned int u32x4;

#define NSEQ 1024
#define SLEN 100
#define HID  512

union HU { u32x4 u; bf16x8 h; };

__device__ __forceinline__ float sigf(float x) { return 1.0f / (1.0f + __expf(-x)); }
__device__ __forceinline__ float tanh_(float x) { return 1.0f - 2.0f / (__expf(2.0f * x) + 1.0f); }

__device__ __forceinline__ bf16x8 cvt8(float4 a, float4 b) {
    bf16x8 v;
    v[0] = (__bf16)a.x; v[1] = (__bf16)a.y; v[2] = (__bf16)a.z; v[3] = (__bf16)a.w;
    v[4] = (__bf16)b.x; v[5] = (__bf16)b.y; v[6] = (__bf16)b.z; v[7] = (__bf16)b.w;
    return v;
}

// ---------------------------------------------------------------------------
// Embedding GEMM: emb[t][seq][h] = sum_d x[seq][t][d] * W_e[h][d] + b_e[h]
// ---------------------------------------------------------------------------
__global__ __launch_bounds__(256)
void embed_kernel(const float* __restrict__ x, const float* __restrict__ We,
                  const float* __restrict__ be, bf16_t* __restrict__ emb)
{
    __shared__ bf16_t bsm[8 * 256 * 8];   // [q=k/8][col][8] bf16 = 32 KB
    const int bid = blockIdx.x;
    const int rowblk = bid >> 1;
    const int col0 = (bid & 1) << 8;
    const int tid = threadIdx.x;

    {
        const int col = tid;  // 0..255
        const float* src = We + (size_t)(col0 + col) * 64;
        #pragma unroll
        for (int q = 0; q < 8; ++q) {
            float4 f0 = *(const float4*)(src + q * 8);
            float4 f1 = *(const float4*)(src + q * 8 + 4);
            *(bf16x8*)&bsm[(q * 256 + col) * 8] = cvt8(f0, f1);
        }
    }
    __syncthreads();

    const int l = tid & 63, w = tid >> 6;
    const int lo = l & 15, hi = l >> 4;
    const int rowbase = rowblk * 64 + w * 16;
    const int row_a = rowbase + lo;
    const int seq = row_a & (NSEQ - 1);
    const int t = row_a >> 10;
    const float* xrow = x + ((size_t)seq * SLEN + t) * 64;

    bf16x8 a0, a1;
    {
        const float* p = xrow + hi * 8;
        a0 = cvt8(*(const float4*)p, *(const float4*)(p + 4));
        p = xrow + 32 + hi * 8;
        a1 = cvt8(*(const float4*)p, *(const float4*)(p + 4));
    }

    #pragma unroll
    for (int nf = 0; nf < 16; ++nf) {
        f32x4 acc = {0.f, 0.f, 0.f, 0.f};
        bf16x8 b0 = *(const bf16x8*)&bsm[((0 * 4 + hi) * 256 + nf * 16 + lo) * 8];
        bf16x8 b1 = *(const bf16x8*)&bsm[((1 * 4 + hi) * 256 + nf * 16 + lo) * 8];
        acc = __builtin_amdgcn_mfma_f32_16x16x32_bf16(a0, b0, acc, 0, 0, 0);
        acc = __builtin_amdgcn_mfma_f32_16x16x32_bf16(a1, b1, acc, 0, 0, 0);
        const int col = col0 + nf * 16 + lo;
        const float bias = be[col];
        #pragma unroll
        for (int r = 0; r < 4; ++r) {
            const int rr = rowbase + hi * 4 + r;
            emb[(size_t)rr * HID + col] = (bf16_t)(acc[r] + bias);
        }
    }
}

// ---------------------------------------------------------------------------
// Persistent masked-LSTM. 256 blocks x 512 threads, 128 KB LDS, 1 block/CU.
// Group m = bid&7 (32 blocks, XCD-local with round-robin dispatch; verified
// at runtime via HW_REG_XCC_ID). Fast path: h exchanged via L1-bypass (sc0)
// loads through the shared per-XCD L2 — no per-step L2 invalidate/writeback.
// Agent-scope fallback if the group spans XCDs.
// Wave = 16 seqs x 64 gate-cols (4 N-frags = i,f,g,o at 16 units); cell
// update fully lane-local; weights LDS-resident. h-loads pipelined with
// counted vmcnt(12/8/4/0) (T4); sched_barrier(0) after each wait (rule #18).
// R17 = R13 verbatim (best: 946 us). R14/R15/R16 all proved the allocator's
// 128 arch-VGPR cap immovable (launch_bounds, waves_per_eu(2,2), AGPR
// parking -> all spill 136 MB to scratch). R13 is register-optimal:
// (a) e-loads exec-masked per lane (mb=0 lanes skip the fetch);
// (b) B-frag register cache for kt 0,1 (16 frags, fits the 128 cap).
// ---------------------------------------------------------------------------
__global__ __launch_bounds__(512)
void lstm_kernel(const bf16_t* __restrict__ emb, const int* __restrict__ mask,
                 const float* __restrict__ Wih, const float* __restrict__ Whh,
                 const float* __restrict__ bih, const float* __restrict__ bhh,
                 const float* __restrict__ h0, const float* __restrict__ c0,
                 bf16_t* __restrict__ hbuf,        // [2][1024][512] bf16
                 unsigned int* __restrict__ cnt,   // [0..511] counters, [512..519] xcd masks
                 float* __restrict__ out)
{
    extern __shared__ bf16_t wsm[];   // [q=k/8 (128)][col (64)][8] = 128 KB
    const int bid = blockIdx.x;
    const int m = bid & 7;            // group (XCD-local with round-robin dispatch)
    const int jsl = bid >> 3;         // 0..31
    const int jbase = jsl * 16;       // 16 hidden units per block
    const int tid = threadIdx.x;

    // publish this block's XCD id into the group's mask (before init arrival)
    unsigned xcc = 0;
    asm volatile("s_getreg_b32 %0, hwreg(HW_REG_XCC_ID)" : "=s"(xcc));
    if (tid == 0)
        __hip_atomic_fetch_or(&cnt[512 + m], 1u << (xcc & 31u),
                              __ATOMIC_RELAXED, __HIP_MEMORY_SCOPE_AGENT);

    // ---- stage weight slice: wsm[q][col][e] = Wcat[G(col)][q*8+e] ----
    {
        const int col = tid & 63;
        const int qg = tid >> 6;          // 0..7
        const int grp = col >> 4;
        const int jj = col & 15;
        const int G = grp * 512 + jbase + jj;
        #pragma unroll
        for (int i = 0; i < 16; ++i) {
            const int q = qg * 16 + i;    // 0..127
            const int k0 = q * 8;
            const float* src = (k0 < 512) ? (Wih + (size_t)G * 512 + k0)
                                          : (Whh + (size_t)G * 512 + (k0 - 512));
            float4 f0 = *(const float4*)src;
            float4 f1 = *(const float4*)(src + 4);
            *(bf16x8*)&wsm[(q * 64 + col) * 8] = cvt8(f0, f1);
        }
    }

    const int lane = tid & 63, w = tid >> 6;
    const int lo = lane & 15, hi = lane >> 4;
    const int seqbase = m * 128 + w * 16;
    const int jg = jbase + lo;
    const int seq_a = seqbase + lo;       // this lane's A row
    const int koff = hi * 8;

    float bs[4];
    #pragma unroll
    for (int g = 0; g < 4; ++g) bs[g] = bih[g * 512 + jg] + bhh[g * 512 + jg];

    // init c and h(0) = mask0 ? emb0 : h0
    float c_reg[4];
    const float c0v = c0[jg], h0v = h0[jg];
    #pragma unroll
    for (int r = 0; r < 4; ++r) {
        const int seq = seqbase + hi * 4 + r;
        c_reg[r] = c0v;
        const int mb0 = mask[(size_t)seq * SLEN + 0];
        const float e0 = (float)emb[(size_t)seq * HID + jg];
        hbuf[(size_t)seq * HID + jg] = (bf16_t)(mb0 ? e0 : h0v);
    }
    __syncthreads();
    if (tid == 0)
        __hip_atomic_fetch_add(&cnt[m * 64], 1u, __ATOMIC_RELEASE,
                               __HIP_MEMORY_SCOPE_AGENT);

    #define BFRAG_L(kt, nf) (*(const bf16x8*)&wsm[(((kt) * 4 + hi) * 64 + (nf) * 16 + lo) * 8])
    #define BFRAG_H(kt, nf) (*(const bf16x8*)&wsm[((((kt) + 16) * 4 + hi) * 64 + (nf) * 16 + lo) * 8])

    // ---- persistent B-frag register cache for kt 0,1 (step-invariant) ----
    HU bcL[2][4], bcH[2][4];
    #pragma unroll
    for (int kt = 0; kt < 2; ++kt) {
        #pragma unroll
        for (int nf = 0; nf < 4; ++nf) {
            bcL[kt][nf].h = BFRAG_L(kt, nf);
            bcH[kt][nf].h = BFRAG_H(kt, nf);
            asm volatile("" : "+v"(bcL[kt][nf].u));   // pin: no remat from LDS
            asm volatile("" : "+v"(bcH[kt][nf].u));
        }
    }

    bool fast = false;

    for (int t = 0; t < SLEN; ++t) {
        // ---- prefetch (h-independent) before the barrier: mask + emb frags.
        //      e-loads exec-masked: mb=0 lanes never use ex, so skip the fetch.
        const int mb = mask[(size_t)seq_a * SLEN + t];
        const bf16_t* erow = emb + ((size_t)t * NSEQ + seq_a) * HID + koff;
        bf16x8 ex[16];
        if (mb) {
            #pragma unroll
            for (int kt = 0; kt < 16; ++kt)
                ex[kt] = *(const bf16x8*)(erow + kt * 32);
        }

        // ---- group barrier ----
        if (tid == 0) {
            const unsigned target = 32u * (unsigned)(t + 1);
            unsigned it = 0;
            while (__hip_atomic_load(&cnt[m * 64], __ATOMIC_RELAXED,
                                     __HIP_MEMORY_SCOPE_AGENT) < target &&
                   ++it < (1u << 27)) {
                __builtin_amdgcn_s_sleep(1);
            }
            if (!fast)   // slow path: agent acquire (L2 invalidate)
                (void)__hip_atomic_load(&cnt[m * 64], __ATOMIC_ACQUIRE,
                                        __HIP_MEMORY_SCOPE_AGENT);
        }
        __syncthreads();
        if (t == 0) {
            const unsigned gm = __hip_atomic_load(&cnt[512 + m], __ATOMIC_RELAXED,
                                                  __HIP_MEMORY_SCOPE_AGENT);
            fast = (__popc(gm) == 1);   // uniform across block
        }

        const bf16_t* hb_r = hbuf + (size_t)(t & 1) * (NSEQ * HID);
        bf16_t* hb_w = hbuf + (size_t)((t + 1) & 1) * (NSEQ * HID);
        const unsigned long long hrow =
            (unsigned long long)(hb_r + (size_t)seq_a * HID + koff);

        // ---- h loads: issue all 16 (sc0, L1-bypass), consume in 4-kt
        //      segments gated by counted vmcnt (pipelined, T4) ----
        HU h_[16];
        #define HL(i, OFF) \
            asm volatile("global_load_dwordx4 %0, %1, off offset:" OFF " sc0" \
                         : "=v"(h_[i].u) : "v"(hrow));
        HL(0, "0")    HL(1, "64")   HL(2, "128")  HL(3, "192")
        HL(4, "256")  HL(5, "320")  HL(6, "384")  HL(7, "448")
        HL(8, "512")  HL(9, "576")  HL(10, "640") HL(11, "704")
        HL(12, "768") HL(13, "832") HL(14, "896") HL(15, "960")
        #undef HL

        f32x4 acc[4];
        #pragma unroll
        for (int nf = 0; nf < 4; ++nf) acc[nf] = (f32x4){0.f, 0.f, 0.f, 0.f};

        // per-kt body: x-half (select) + h-half, both consuming h_[kt].
        #define KT_ONE(kt, BL0, BL1, BL2, BL3, BH0, BH1, BH2, BH3)                       \
            {                                                                            \
                const bf16x8 a = mb ? ex[kt] : h_[kt].h;                                 \
                acc[0] = __builtin_amdgcn_mfma_f32_16x16x32_bf16(a, BL0, acc[0], 0, 0, 0); \
                acc[1] = __builtin_amdgcn_mfma_f32_16x16x32_bf16(a, BL1, acc[1], 0, 0, 0); \
                acc[2] = __builtin_amdgcn_mfma_f32_16x16x32_bf16(a, BL2, acc[2], 0, 0, 0); \
                acc[3] = __builtin_amdgcn_mfma_f32_16x16x32_bf16(a, BL3, acc[3], 0, 0, 0); \
                acc[0] = __builtin_amdgcn_mfma_f32_16x16x32_bf16(h_[kt].h, BH0, acc[0], 0, 0, 0); \
                acc[1] = __builtin_amdgcn_mfma_f32_16x16x32_bf16(h_[kt].h, BH1, acc[1], 0, 0, 0); \
                acc[2] = __builtin_amdgcn_mfma_f32_16x16x32_bf16(h_[kt].h, BH2, acc[2], 0, 0, 0); \
                acc[3] = __builtin_amdgcn_mfma_f32_16x16x32_bf16(h_[kt].h, BH3, acc[3], 0, 0, 0); \
            }
        #define KT_REG(kt) KT_ONE(kt, bcL[kt][0].h, bcL[kt][1].h, bcL[kt][2].h, bcL[kt][3].h, \
                                       bcH[kt][0].h, bcH[kt][1].h, bcH[kt][2].h, bcH[kt][3].h)
        #define KT_LDS(kt) KT_ONE(kt, BFRAG_L(kt, 0), BFRAG_L(kt, 1), BFRAG_L(kt, 2), BFRAG_L(kt, 3), \
                                       BFRAG_H(kt, 0), BFRAG_H(kt, 1), BFRAG_H(kt, 2), BFRAG_H(kt, 3))
        #define WAITSB(VMC) \
            asm volatile("s_waitcnt vmcnt(" VMC ")" ::: "memory"); \
            __builtin_amdgcn_sched_barrier(0);

        WAITSB("12")
        KT_REG(0) KT_REG(1)
        KT_LDS(2) KT_LDS(3)
        WAITSB("8")
        KT_LDS(4) KT_LDS(5) KT_LDS(6) KT_LDS(7)
        WAITSB("4")
        KT_LDS(8) KT_LDS(9) KT_LDS(10) KT_LDS(11)
        WAITSB("0")
        KT_LDS(12) KT_LDS(13) KT_LDS(14) KT_LDS(15)
        #undef KT_ONE
        #undef KT_REG
        #undef KT_LDS
        #undef WAITSB

        // ---- lane-local LSTM cell update (acc[0..3] = i,f,g,o at unit jg) ----
        #pragma unroll
        for (int r = 0; r < 4; ++r) {
            const float iv = acc[0][r] + bs[0];
            const float fv = acc[1][r] + bs[1];
            const float gv = acc[2][r] + bs[2];
            const float ov = acc[3][r] + bs[3];
            const float cn = sigf(fv) * c_reg[r] + sigf(iv) * tanh_(gv);
            c_reg[r] = cn;
            const float hv = sigf(ov) * tanh_(cn);
            const int s = seqbase + hi * 4 + r;
            hb_w[(size_t)s * HID + jg] = (bf16_t)hv;
            if (t == SLEN - 1) out[(size_t)s * HID + jg] = hv;
        }
        __syncthreads();   // drains h stores (vmcnt 0) before the counter bump
        if (tid == 0) {
            if (fast)
                __hip_atomic_fetch_add(&cnt[m * 64], 1u, __ATOMIC_RELAXED,
                                       __HIP_MEMORY_SCOPE_AGENT);
            else
                __hip_atomic_fetch_add(&cnt[m * 64], 1u, __ATOMIC_RELEASE,
                                       __HIP_MEMORY_SCOPE_AGENT);
        }
    }
    #undef BFRAG_L
    #undef BFRAG_H
}

// ---------------------------------------------------------------------------
extern "C" void kernel_launch(void* const* d_in, const int* in_sizes, int n_in,
                              void* d_out, int out_size, void* d_ws, size_t ws_size,
                              hipStream_t stream)
{
    const float* x    = (const float*)d_in[0];
    const int*   mask = (const int*)d_in[1];
    const float* We   = (const float*)d_in[2];
    const float* be   = (const float*)d_in[3];
    const float* Wih  = (const float*)d_in[4];
    const float* Whh  = (const float*)d_in[5];
    const float* bih  = (const float*)d_in[6];
    const float* bhh  = (const float*)d_in[7];
    const float* h0   = (const float*)d_in[8];
    const float* c0   = (const float*)d_in[9];
    float* out = (float*)d_out;

    unsigned char* ws = (unsigned char*)d_ws;
    unsigned int* cnt = (unsigned int*)ws;                       // 4 KB
    bf16_t* hbuf = (bf16_t*)(ws + 4096);                         // 2 MB
    bf16_t* emb  = (bf16_t*)(ws + 4096 + (size_t)2 * NSEQ * HID * 2);  // ~100 MB

    hipMemsetAsync(cnt, 0, 4096, stream);

    embed_kernel<<<3200, 256, 0, stream>>>(x, We, be, emb);

    hipFuncSetAttribute(reinterpret_cast<const void*>(lstm_kernel),
                        hipFuncAttributeMaxDynamicSharedMemorySize, 131072);
    lstm_kernel<<<256, 512, 131072, stream>>>(emb, mask, Wih, Whh, bih, bhh,
                                              h0, c0, hbuf, cnt, out);
}